// Round 1
// baseline (2791.934 us; speedup 1.0000x reference)
//
#include <hip/hip_runtime.h>
#include <math.h>

#define B_ 32
#define S_ 128
#define C_ 384
#define H_ 8
#define W_ 512
#define NKV 4096   // H_*W_

// ---------------------------------------------------------------- mean over H
__global__ __launch_bounds__(256) void mean_kernel(const float* __restrict__ kv,
                                                   float* __restrict__ dec0) {
    int v = blockIdx.x * blockDim.x + threadIdx.x;  // float4 index over (B,W,C)
    int total = B_ * W_ * (C_ / 4);
    if (v >= total) return;
    int c4  = v % (C_ / 4);
    int row = v / (C_ / 4);      // b*W + w
    int b = row / W_;
    int w = row % W_;
    const float4* src = (const float4*)kv + (size_t)(b * NKV + w) * (C_ / 4) + c4;
    float4 s = {0.f, 0.f, 0.f, 0.f};
#pragma unroll
    for (int h = 0; h < H_; ++h) {
        float4 t = src[(size_t)h * W_ * (C_ / 4)];
        s.x += t.x; s.y += t.y; s.z += t.z; s.w += t.w;
    }
    s.x *= 0.125f; s.y *= 0.125f; s.z *= 0.125f; s.w *= 0.125f;
    ((float4*)dec0)[v] = s;
}

// ---------------------------------------------------------------- SGEMM 64x64
// C[m,n] = act(alpha * sum_k A[m,k]*Wt[k,n] + bias[n]); act: 0=none, 1=tanh
// M%64==0, N%64==0, K%16==0 guaranteed by problem dims.
__global__ __launch_bounds__(256) void sgemm_kernel(
    const float* __restrict__ A, const float* __restrict__ Wt,
    const float* __restrict__ bias, float* __restrict__ Cout,
    int M, int N, int K, float alpha, int act)
{
    __shared__ float As[16][68];   // [k][m], padded to avoid conflicts
    __shared__ float Bs[16][64];   // [k][n]
    const int tid = threadIdx.x;       // 0..255
    const int tx = tid & 15;           // col group
    const int ty = tid >> 4;           // row group
    const int bm = blockIdx.y * 64;
    const int bn = blockIdx.x * 64;
    const int lr = tid >> 4;           // A-load row 0..15
    const int lc = tid & 15;           // A-load col (k) 0..15
    const int br = tid >> 6;           // B-load k 0..3
    const int bc = tid & 63;           // B-load col 0..63

    float acc[4][4] = {};

    for (int k0 = 0; k0 < K; k0 += 16) {
#pragma unroll
        for (int i = 0; i < 4; ++i)
            As[lc][lr + 16 * i] = A[(size_t)(bm + lr + 16 * i) * K + k0 + lc];
#pragma unroll
        for (int i = 0; i < 4; ++i)
            Bs[br + 4 * i][bc] = Wt[(size_t)(k0 + br + 4 * i) * N + bn + bc];
        __syncthreads();
#pragma unroll
        for (int kk = 0; kk < 16; ++kk) {
            float4 av = *(const float4*)&As[kk][ty * 4];
            float4 bv = *(const float4*)&Bs[kk][tx * 4];
            float a_[4] = {av.x, av.y, av.z, av.w};
            float b_[4] = {bv.x, bv.y, bv.z, bv.w};
#pragma unroll
            for (int i = 0; i < 4; ++i)
#pragma unroll
                for (int j = 0; j < 4; ++j)
                    acc[i][j] = fmaf(a_[i], b_[j], acc[i][j]);
        }
        __syncthreads();
    }

#pragma unroll
    for (int i = 0; i < 4; ++i) {
        int m = bm + ty * 4 + i;
        float4 v4;
        float* vv = (float*)&v4;
#pragma unroll
        for (int j = 0; j < 4; ++j) {
            float v = acc[i][j] * alpha;
            if (bias) v += bias[bn + tx * 4 + j];
            if (act == 1) v = tanhf(v);
            vv[j] = v;
        }
        *(float4*)&Cout[(size_t)m * N + bn + tx * 4] = v4;
    }
}

static inline void gemm(hipStream_t st, const float* A, const float* Wt,
                        const float* bias, float* Cout,
                        int M, int N, int K, float alpha, int act) {
    dim3 grid(N / 64, M / 64), block(256);
    sgemm_kernel<<<grid, block, 0, st>>>(A, Wt, bias, Cout, M, N, K, alpha, act);
}

// ---------------------------------------------------------------- LayerNorm
__global__ __launch_bounds__(128) void ln_kernel(const float* __restrict__ X,
    const float* __restrict__ g, const float* __restrict__ bb,
    float* __restrict__ Y) {
    int row = blockIdx.x;
    const float* x = X + (size_t)row * C_;
    float* y = Y + (size_t)row * C_;
    int t = threadIdx.x;
    float v0 = x[t], v1 = x[t + 128], v2 = x[t + 256];
    float s = v0 + v1 + v2, sq = v0 * v0 + v1 * v1 + v2 * v2;
    __shared__ float rs[128], rq[128];
    rs[t] = s; rq[t] = sq; __syncthreads();
    if (t < 64) {
        s = rs[t] + rs[t + 64]; sq = rq[t] + rq[t + 64];
        for (int o = 32; o; o >>= 1) { s += __shfl_down(s, o); sq += __shfl_down(sq, o); }
        if (t == 0) { rs[0] = s; rq[0] = sq; }
    }
    __syncthreads();
    float mean = rs[0] * (1.0f / C_);
    float var  = rq[0] * (1.0f / C_) - mean * mean;
    float inv  = rsqrtf(var + 1e-6f);
    y[t]       = (v0 - mean) * inv * g[t]       + bb[t];
    y[t + 128] = (v1 - mean) * inv * g[t + 128] + bb[t + 128];
    y[t + 256] = (v2 - mean) * inv * g[t + 256] + bb[t + 256];
}

// -------------------------------------------------- 2-head cross-attention
// qp: (B,S,C) already scaled by 1/sqrt(192); kvp: (B,N,768) (k|v per row);
// xout: (B,S,C). One block per (b,h,s), 192 threads.
__global__ __launch_bounds__(192) void ca_attn_kernel(
    const float* __restrict__ qp, const float* __restrict__ kvp,
    float* __restrict__ xout, int N)
{
    int blk = blockIdx.x;          // b*2*S + h*S + s
    int s = blk % S_;
    int h = (blk / S_) & 1;
    int b = blk / (2 * S_);
    int t = threadIdx.x;
    __shared__ float qrow[192];
    __shared__ float sc[512];
    __shared__ float red[192];
    qrow[t] = qp[((size_t)(b * S_ + s)) * C_ + h * 192 + t];
    __syncthreads();
    const float* kbase = kvp + ((size_t)b * N) * 768 + h * 192;
    float lmax = -1e30f;
    for (int n = t; n < N; n += 192) {
        const float* krow = kbase + (size_t)n * 768;
        float acc = 0.f;
#pragma unroll
        for (int d = 0; d < 192; d += 4) {
            float4 kq = *(const float4*)(krow + d);
            float4 qq = *(const float4*)(qrow + d);
            acc += kq.x * qq.x + kq.y * qq.y + kq.z * qq.z + kq.w * qq.w;
        }
        sc[n] = acc;
        lmax = fmaxf(lmax, acc);
    }
    red[t] = lmax; __syncthreads();
    if (t < 64) {
        float m = fmaxf(red[t], fmaxf(red[t + 64], red[t + 128]));
        for (int o = 32; o; o >>= 1) m = fmaxf(m, __shfl_down(m, o));
        if (t == 0) red[0] = m;
    }
    __syncthreads();
    float gmax = red[0];
    __syncthreads();
    float lsum = 0.f;
    for (int n = t; n < N; n += 192) {
        float e = expf(sc[n] - gmax);
        sc[n] = e;
        lsum += e;
    }
    red[t] = lsum; __syncthreads();
    if (t < 64) {
        float ssum = red[t] + red[t + 64] + red[t + 128];
        for (int o = 32; o; o >>= 1) ssum += __shfl_down(ssum, o);
        if (t == 0) red[0] = ssum;
    }
    __syncthreads();
    float rinv = 1.0f / red[0];
    const float* vbase = kvp + ((size_t)b * N) * 768 + 384 + h * 192 + t;
    float o = 0.f;
    for (int n = 0; n < N; n += 4) {
        o += sc[n]     * vbase[(size_t)n * 768]
           + sc[n + 1] * vbase[(size_t)(n + 1) * 768]
           + sc[n + 2] * vbase[(size_t)(n + 2) * 768]
           + sc[n + 3] * vbase[(size_t)(n + 3) * 768];
    }
    xout[((size_t)(b * S_ + s)) * C_ + h * 192 + t] = o * rinv;
}

// -------------------------------------------------- main gauss-windowed attn
// qh: (B,S,C) scaled by 1/sqrt(384); kvm: (B,W,768); pt: (B*S). One block per
// (b,s), 384 threads. gauss multiplies pre-softmax scores.
__global__ __launch_bounds__(384) void main_attn_kernel(
    const float* __restrict__ qh, const float* __restrict__ kvm,
    const float* __restrict__ pt, float* __restrict__ xout)
{
    int blk = blockIdx.x;  // b*S + s
    int b = blk / S_;
    int t = threadIdx.x;
    __shared__ float qrow[384];
    __shared__ float sc[512];
    __shared__ float red[384];
    qrow[t] = qh[(size_t)blk * C_ + t];
    __syncthreads();
    float p = pt[blk];
    const float* kbase = kvm + ((size_t)b * W_) * 768;
    float lmax = -1e30f;
    for (int w = t; w < W_; w += 384) {
        const float* krow = kbase + (size_t)w * 768;
        float acc = 0.f;
#pragma unroll
        for (int d = 0; d < 384; d += 4) {
            float4 kq = *(const float4*)(krow + d);
            float4 qq = *(const float4*)(qrow + d);
            acc += kq.x * qq.x + kq.y * qq.y + kq.z * qq.z + kq.w * qq.w;
        }
        float dw = (float)w - p;
        acc *= expf(dw * dw * (-1.0f / 18.0f));
        sc[w] = acc;
        lmax = fmaxf(lmax, acc);
    }
    red[t] = lmax; __syncthreads();
    if (t < 64) {
        float m = red[t];
#pragma unroll
        for (int j = 1; j < 6; ++j) m = fmaxf(m, red[t + 64 * j]);
        for (int o = 32; o; o >>= 1) m = fmaxf(m, __shfl_down(m, o));
        if (t == 0) red[0] = m;
    }
    __syncthreads();
    float gmax = red[0];
    __syncthreads();
    float lsum = 0.f;
    for (int w = t; w < W_; w += 384) { float e = expf(sc[w] - gmax); sc[w] = e; lsum += e; }
    red[t] = lsum; __syncthreads();
    if (t < 64) {
        float ssum = red[t];
#pragma unroll
        for (int j = 1; j < 6; ++j) ssum += red[t + 64 * j];
        for (int o = 32; o; o >>= 1) ssum += __shfl_down(ssum, o);
        if (t == 0) red[0] = ssum;
    }
    __syncthreads();
    float rinv = 1.0f / red[0];
    const float* vbase = kvm + ((size_t)b * W_) * 768 + 384 + t;
    float o = 0.f;
    for (int w = 0; w < W_; w += 4) {
        o += sc[w]     * vbase[(size_t)w * 768]
           + sc[w + 1] * vbase[(size_t)(w + 1) * 768]
           + sc[w + 2] * vbase[(size_t)(w + 2) * 768]
           + sc[w + 3] * vbase[(size_t)(w + 3) * 768];
    }
    xout[(size_t)blk * C_ + t] = o * rinv;
}

// ---------------------------------------------------------------- p_t head
__global__ __launch_bounds__(128) void pt_kernel(const float* __restrict__ T,
    const float* __restrict__ vpw, const float* __restrict__ vpb,
    float* __restrict__ out) {
    int row = blockIdx.x;
    int t = threadIdx.x;
    const float* x = T + (size_t)row * C_;
    float s = x[t] * vpw[t] + x[t + 128] * vpw[t + 128] + x[t + 256] * vpw[t + 256];
    __shared__ float red[128];
    red[t] = s; __syncthreads();
    if (t < 64) {
        s = red[t] + red[t + 64];
        for (int o = 32; o; o >>= 1) s += __shfl_down(s, o);
        if (t == 0) {
            float z = s + vpb[0];
            out[row] = 512.0f / (1.0f + expf(-z));
        }
    }
}

// ---------------------------------------------------------------- launch
extern "C" void kernel_launch(void* const* d_in, const int* in_sizes, int n_in,
                              void* d_out, int out_size, void* d_ws, size_t ws_size,
                              hipStream_t stream) {
    const float* q     = (const float*)d_in[0];
    const float* kv    = (const float*)d_in[1];
    const float* Wq    = (const float*)d_in[2];
    const float* Wkv   = (const float*)d_in[3];
    const float* Wproj = (const float*)d_in[4];
    const float* bproj = (const float*)d_in[5];
    const float* Wp_w  = (const float*)d_in[6];
    const float* Wp_b  = (const float*)d_in[7];
    const float* vp_w  = (const float*)d_in[8];
    const float* vp_b  = (const float*)d_in[9];
    const float* Wqpos = (const float*)d_in[10];
    const float* bqpos = (const float*)d_in[11];
    const float* Wrctc = (const float*)d_in[12];
    const float* brctc = (const float*)d_in[13];
    const float* ca1_Wq    = (const float*)d_in[14];
    const float* ca1_Wkv   = (const float*)d_in[15];
    const float* ca1_Wproj = (const float*)d_in[16];
    const float* ca1_bproj = (const float*)d_in[17];
    const float* ca2_Wq    = (const float*)d_in[18];
    const float* ca2_Wkv   = (const float*)d_in[19];
    const float* ca2_Wproj = (const float*)d_in[20];
    const float* ca2_bproj = (const float*)d_in[21];
    const float* g_q1  = (const float*)d_in[22];
    const float* b_q1  = (const float*)d_in[23];
    const float* g_kv1 = (const float*)d_in[24];
    const float* b_kv1 = (const float*)d_in[25];
    const float* g_q2  = (const float*)d_in[26];
    const float* b_q2  = (const float*)d_in[27];
    const float* g_kv2 = (const float*)d_in[28];
    const float* b_kv2 = (const float*)d_in[29];
    float* out = (float*)d_out;
    float* ws  = (float*)d_ws;

    // workspace layout (floats); kvp slot reused: ca1 kv-proj (3.1M), then
    // ca2 kv-proj (12.6M), then main k/v = dec@Wkv (12.6M). total ~157 MB.
    float* dec0 = ws;                    // 6291456
    float* dec  = dec0 + 6291456;        // 6291456
    float* qh   = dec  + 6291456;        // 1572864
    float* p    = qh   + 1572864;        // 1572864
    float* t1   = p    + 1572864;        // 1572864
    float* t2   = t1   + 1572864;        // 6291456 (max: LN of dec)
    float* qp   = t2   + 6291456;        // 1572864
    float* kvp  = qp   + 1572864;        // 12582912
    float* x    = kvp  + 12582912;       // 1572864
    float* ptb  = x    + 1572864;        // 4096

    const float rs384 = 0.05103103630798288f;  // 1/sqrt(384)
    const float rs192 = 0.07216878364870323f;  // 1/sqrt(192)

    // 1. dec0 = mean over H of kv
    {
        int total = B_ * W_ * (C_ / 4);
        mean_kernel<<<(total + 255) / 256, 256, 0, stream>>>(kv, dec0);
    }
    // 2. dec = dec0 @ Wrctc + brctc
    gemm(stream, dec0, Wrctc, brctc, dec, B_ * W_, 384, 384, 1.f, 0);
    // 3. qh = (q @ Wq) * 1/sqrt(384)
    gemm(stream, q, Wq, nullptr, qh, B_ * S_, 384, 384, rs384, 0);
    // 4. p = q @ Wqpos + bqpos
    gemm(stream, q, Wqpos, bqpos, p, B_ * S_, 384, 384, 1.f, 0);
    // 5. ca1: LN(p), LN(q)
    ln_kernel<<<B_ * S_, 128, 0, stream>>>(p, g_q1, b_q1, t1);
    ln_kernel<<<B_ * S_, 128, 0, stream>>>(q, g_kv1, b_kv1, t2);
    gemm(stream, t1, ca1_Wq, nullptr, qp, B_ * S_, 384, 384, rs192, 0);
    gemm(stream, t2, ca1_Wkv, nullptr, kvp, B_ * S_, 768, 384, 1.f, 0);
    ca_attn_kernel<<<B_ * 2 * S_, 192, 0, stream>>>(qp, kvp, x, S_);
    gemm(stream, x, ca1_Wproj, ca1_bproj, p, B_ * S_, 384, 384, 1.f, 0);
    // 6. ca2: LN(p), LN(dec)
    ln_kernel<<<B_ * S_, 128, 0, stream>>>(p, g_q2, b_q2, t1);
    ln_kernel<<<B_ * W_, 128, 0, stream>>>(dec, g_kv2, b_kv2, t2);
    gemm(stream, t1, ca2_Wq, nullptr, qp, B_ * S_, 384, 384, rs192, 0);
    gemm(stream, t2, ca2_Wkv, nullptr, kvp, B_ * W_, 768, 384, 1.f, 0);
    ca_attn_kernel<<<B_ * 2 * S_, 192, 0, stream>>>(qp, kvp, x, W_);
    gemm(stream, x, ca2_Wproj, ca2_bproj, p, B_ * S_, 384, 384, 1.f, 0);
    // 7. p_t = sigmoid(tanh(p@Wp_w + Wp_b) @ vp_w + vp_b) * W
    gemm(stream, p, Wp_w, Wp_b, t1, B_ * S_, 384, 384, 1.f, 1);
    pt_kernel<<<B_ * S_, 128, 0, stream>>>(t1, vp_w, vp_b, ptb);
    // 8. main k/v = dec @ Wkv  (into kvp slot, ca2 done with it)
    gemm(stream, dec, Wkv, nullptr, kvp, B_ * W_, 768, 384, 1.f, 0);
    // 9. gauss-windowed attention
    main_attn_kernel<<<B_ * S_, 384, 0, stream>>>(qh, kvp, ptb, x);
    // 10. out = x @ Wproj + bproj
    gemm(stream, x, Wproj, bproj, out, B_ * S_, 384, 384, 1.f, 0);
}

// Round 2
// 1188.638 us; speedup vs baseline: 2.3489x; 2.3489x over previous
//
#include <hip/hip_runtime.h>
#include <hip/hip_bf16.h>
#include <math.h>

#define B_ 32
#define S_ 128
#define C_ 384
#define H_ 8
#define W_ 512
#define NKV 4096   // H_*W_

typedef __attribute__((ext_vector_type(8))) short short8;
typedef __attribute__((ext_vector_type(4))) float floatx4;

static __device__ __forceinline__ ushort f2bf(float v) {
    __hip_bfloat16 h = __float2bfloat16(v);
    return *(ushort*)&h;
}

// ---------------------------------------------------------------- mean over H -> bf16
__global__ __launch_bounds__(256) void mean_kernel(const float* __restrict__ kv,
                                                   ushort* __restrict__ dec0b) {
    int v = blockIdx.x * blockDim.x + threadIdx.x;  // float4 index over (B,W,C)
    int total = B_ * W_ * (C_ / 4);
    if (v >= total) return;
    int c4  = v % (C_ / 4);
    int row = v / (C_ / 4);      // b*W + w
    int b = row / W_;
    int w = row % W_;
    const float4* src = (const float4*)kv + (size_t)(b * NKV + w) * (C_ / 4) + c4;
    float4 s = {0.f, 0.f, 0.f, 0.f};
#pragma unroll
    for (int h = 0; h < H_; ++h) {
        float4 t = src[(size_t)h * W_ * (C_ / 4)];
        s.x += t.x; s.y += t.y; s.z += t.z; s.w += t.w;
    }
    ushort4 o;
    o.x = f2bf(s.x * 0.125f); o.y = f2bf(s.y * 0.125f);
    o.z = f2bf(s.z * 0.125f); o.w = f2bf(s.w * 0.125f);
    ((ushort4*)dec0b)[v] = o;
}

// ---------------------------------------------------------------- cast fp32 -> bf16
__global__ __launch_bounds__(256) void cast_kernel(const float* __restrict__ in,
                                                   ushort* __restrict__ out, int n4) {
    int v = blockIdx.x * blockDim.x + threadIdx.x;
    if (v >= n4) return;
    float4 f = ((const float4*)in)[v];
    ushort4 o;
    o.x = f2bf(f.x); o.y = f2bf(f.y); o.z = f2bf(f.z); o.w = f2bf(f.w);
    ((ushort4*)out)[v] = o;
}

// ------------------------------------------------- weight transpose+cast (K,N)->(N,K)
struct WtDesc { const float* src[12]; ushort* dst[12]; int Kd[12]; int Nd[12]; };
__global__ __launch_bounds__(256) void wtcast_kernel(WtDesc d) {
    int wi = blockIdx.y;
    int idx = blockIdx.x * 256 + threadIdx.x;
    int K = d.Kd[wi], N = d.Nd[wi];
    if (idx >= K * N) return;
    int n = idx / K, k = idx % K;
    d.dst[wi][idx] = f2bf(d.src[wi][(size_t)k * N + n]);
}

// ---------------------------------------------------------------- bf16 MFMA GEMM
// C = act(alpha * A(MxK) @ B(KxN) + bias), B given transposed: Bt (N x K), bf16.
// 128x128 tile, 256 threads = 4 waves (2x2 of 64x64), K step 32.
__global__ __launch_bounds__(256) void bgemm_kernel(
    const ushort* __restrict__ A, const ushort* __restrict__ Bt,
    const float* __restrict__ bias, float* __restrict__ Cout,
    ushort* __restrict__ Cbf, int M, int N, int K, float alpha, int act)
{
    __shared__ ushort As[128 * 40];
    __shared__ ushort Bs[128 * 40];
    const int tid = threadIdx.x;
    const int bm = blockIdx.y * 128, bn = blockIdx.x * 128;
    const int wav = tid >> 6, lane = tid & 63;
    const int wm = (wav >> 1) * 64, wn = (wav & 1) * 64;
    const int lrow = lane & 15, lq = lane >> 4;

    floatx4 acc[4][4] = {};

    const int sr = tid >> 1, sc0 = (tid & 1) * 16;
    const ushort* Ag = A + (size_t)(bm + sr) * K + sc0;
    const ushort* Bg = Bt + (size_t)(bn + sr) * K + sc0;
    ushort* Asw = &As[sr * 40 + sc0];
    ushort* Bsw = &Bs[sr * 40 + sc0];

    for (int k0 = 0; k0 < K; k0 += 32) {
        uint4 a0 = *(const uint4*)(Ag + k0);
        uint4 a1 = *(const uint4*)(Ag + k0 + 8);
        uint4 b0 = *(const uint4*)(Bg + k0);
        uint4 b1 = *(const uint4*)(Bg + k0 + 8);
        __syncthreads();
        *(uint4*)Asw = a0; *(uint4*)(Asw + 8) = a1;
        *(uint4*)Bsw = b0; *(uint4*)(Bsw + 8) = b1;
        __syncthreads();
        short8 af[4], bfr[4];
#pragma unroll
        for (int i = 0; i < 4; ++i)
            af[i] = *(const short8*)&As[(wm + 16 * i + lrow) * 40 + lq * 8];
#pragma unroll
        for (int j = 0; j < 4; ++j)
            bfr[j] = *(const short8*)&Bs[(wn + 16 * j + lrow) * 40 + lq * 8];
#pragma unroll
        for (int i = 0; i < 4; ++i)
#pragma unroll
            for (int j = 0; j < 4; ++j)
                acc[i][j] = __builtin_amdgcn_mfma_f32_16x16x32_bf16(af[i], bfr[j], acc[i][j], 0, 0, 0);
    }

#pragma unroll
    for (int i = 0; i < 4; ++i)
#pragma unroll
        for (int j = 0; j < 4; ++j) {
            int row = bm + wm + 16 * i + lq * 4;
            int col = bn + wn + 16 * j + lrow;
            float bv = bias ? bias[col] : 0.f;
#pragma unroll
            for (int r = 0; r < 4; ++r) {
                float v = acc[i][j][r] * alpha + bv;
                if (act == 1) v = tanhf(v);
                size_t off = (size_t)(row + r) * N + col;
                Cout[off] = v;
                if (Cbf) Cbf[off] = f2bf(v);
            }
        }
}

static inline void bgemm(hipStream_t st, const ushort* A, const ushort* Bt,
                         const float* bias, float* Cout, ushort* Cbf,
                         int M, int N, int K, float alpha, int act) {
    dim3 grid(N / 128, M / 128), block(256);
    bgemm_kernel<<<grid, block, 0, st>>>(A, Bt, bias, Cout, Cbf, M, N, K, alpha, act);
}

// ---------------------------------------------------------------- LayerNorm -> bf16
__global__ __launch_bounds__(128) void ln_kernel(const float* __restrict__ X,
    const float* __restrict__ g, const float* __restrict__ bb,
    ushort* __restrict__ Y) {
    int row = blockIdx.x;
    const float* x = X + (size_t)row * C_;
    ushort* y = Y + (size_t)row * C_;
    int t = threadIdx.x;
    float v0 = x[t], v1 = x[t + 128], v2 = x[t + 256];
    float s = v0 + v1 + v2, sq = v0 * v0 + v1 * v1 + v2 * v2;
    __shared__ float rs[128], rq[128];
    rs[t] = s; rq[t] = sq; __syncthreads();
    if (t < 64) {
        s = rs[t] + rs[t + 64]; sq = rq[t] + rq[t + 64];
        for (int o = 32; o; o >>= 1) { s += __shfl_down(s, o); sq += __shfl_down(sq, o); }
        if (t == 0) { rs[0] = s; rq[0] = sq; }
    }
    __syncthreads();
    float mean = rs[0] * (1.0f / C_);
    float var  = rq[0] * (1.0f / C_) - mean * mean;
    float inv  = rsqrtf(var + 1e-6f);
    y[t]       = f2bf((v0 - mean) * inv * g[t]       + bb[t]);
    y[t + 128] = f2bf((v1 - mean) * inv * g[t + 128] + bb[t + 128]);
    y[t + 256] = f2bf((v2 - mean) * inv * g[t + 256] + bb[t + 256]);
}

// ---------------------------------------------------------------- fused attention
// qp: (B,S,NH*HD) fp32 pre-scaled; kvp: (B,N,2*NH*HD) fp32; out bf16 (B,S,NH*HD).
// Block = (b, h, 8 s-rows). 256 threads. GAUSS: multiply scores by gaussian window.
template<int HD, int NH, int GAUSS>
__global__ __launch_bounds__(256) void attn_kernel(
    const float* __restrict__ qp, const float* __restrict__ kvp,
    const float* __restrict__ ptv, ushort* __restrict__ xout, int N)
{
    const int C2 = 2 * NH * HD;
    const int CC = NH * HD;
    const int nst = S_ / 8;
    int st = blockIdx.x % nst;
    int h  = (blockIdx.x / nst) % NH;
    int b  = blockIdx.x / (nst * NH);
    int s0 = st * 8;
    int t = threadIdx.x;

    __shared__ float qs[8][HD];
    __shared__ float sc[8][512];
    __shared__ float ps[8];
    __shared__ float rsum[8];

    for (int i = t; i < 8 * HD; i += 256) {
        int s = i / HD, d = i % HD;
        qs[s][d] = qp[((size_t)(b * S_ + s0 + s)) * CC + h * HD + d];
    }
    if (GAUSS && t < 8) ps[t] = ptv[b * S_ + s0 + t];
    __syncthreads();

    // ---- phase 1: scores (each thread: 4 s-rows x NW w-columns)
    {
        const int g = t >> 7;              // 0: rows 0-3, 1: rows 4-7
        const int wbase = t & 127;
        const int NW = N >> 7;             // 1 (N=128) or 4 (N=512)
        const float* kb = kvp + ((size_t)b * N) * C2 + h * HD;
        float acc[4][4] = {};
        const float* krow[4];
#pragma unroll
        for (int k = 0; k < 4; ++k)
            krow[k] = kb + (size_t)(wbase + (k < NW ? k : 0) * 128) * C2;
        for (int d = 0; d < HD; d += 4) {
            float4 q0 = *(const float4*)&qs[g * 4 + 0][d];
            float4 q1 = *(const float4*)&qs[g * 4 + 1][d];
            float4 q2 = *(const float4*)&qs[g * 4 + 2][d];
            float4 q3 = *(const float4*)&qs[g * 4 + 3][d];
#pragma unroll
            for (int k = 0; k < 4; ++k) {
                if (k >= NW) break;
                float4 kf = *(const float4*)(krow[k] + d);
                acc[0][k] += q0.x * kf.x + q0.y * kf.y + q0.z * kf.z + q0.w * kf.w;
                acc[1][k] += q1.x * kf.x + q1.y * kf.y + q1.z * kf.z + q1.w * kf.w;
                acc[2][k] += q2.x * kf.x + q2.y * kf.y + q2.z * kf.z + q2.w * kf.w;
                acc[3][k] += q3.x * kf.x + q3.y * kf.y + q3.z * kf.z + q3.w * kf.w;
            }
        }
#pragma unroll
        for (int k = 0; k < 4; ++k) {
            if (k >= NW) break;
            int w = wbase + k * 128;
#pragma unroll
            for (int s = 0; s < 4; ++s) {
                float v = acc[s][k];
                if (GAUSS) {
                    float dw = (float)w - ps[g * 4 + s];
                    v *= expf(dw * dw * (-1.0f / 18.0f));
                }
                sc[g * 4 + s][w] = v;
            }
        }
    }
    __syncthreads();

    // ---- softmax: wave wav handles rows 2*wav, 2*wav+1
    {
        int wav = t >> 6, lane = t & 63;
#pragma unroll
        for (int rr = 0; rr < 2; ++rr) {
            int r = wav * 2 + rr;
            float m = -1e30f;
            for (int w = lane; w < N; w += 64) m = fmaxf(m, sc[r][w]);
            for (int o = 32; o; o >>= 1) m = fmaxf(m, __shfl_xor(m, o));
            float ssum = 0.f;
            for (int w = lane; w < N; w += 64) {
                float e = expf(sc[r][w] - m);
                sc[r][w] = e; ssum += e;
            }
            for (int o = 32; o; o >>= 1) ssum += __shfl_xor(ssum, o);
            if (lane == 0) rsum[r] = 1.0f / ssum;
        }
    }
    __syncthreads();

    // ---- PV: thread handles d-columns t, t+256, ...
    for (int d = t; d < HD; d += 256) {
        const float* vb = kvp + ((size_t)b * N) * C2 + NH * HD + h * HD + d;
        float o[8] = {};
        for (int w = 0; w < N; w += 4) {
            float4 p0 = *(const float4*)&sc[0][w];
            float4 p1 = *(const float4*)&sc[1][w];
            float4 p2 = *(const float4*)&sc[2][w];
            float4 p3 = *(const float4*)&sc[3][w];
            float4 p4 = *(const float4*)&sc[4][w];
            float4 p5 = *(const float4*)&sc[5][w];
            float4 p6 = *(const float4*)&sc[6][w];
            float4 p7 = *(const float4*)&sc[7][w];
            float v0 = vb[(size_t)w * C2];
            float v1 = vb[(size_t)(w + 1) * C2];
            float v2 = vb[(size_t)(w + 2) * C2];
            float v3 = vb[(size_t)(w + 3) * C2];
            o[0] += p0.x * v0 + p0.y * v1 + p0.z * v2 + p0.w * v3;
            o[1] += p1.x * v0 + p1.y * v1 + p1.z * v2 + p1.w * v3;
            o[2] += p2.x * v0 + p2.y * v1 + p2.z * v2 + p2.w * v3;
            o[3] += p3.x * v0 + p3.y * v1 + p3.z * v2 + p3.w * v3;
            o[4] += p4.x * v0 + p4.y * v1 + p4.z * v2 + p4.w * v3;
            o[5] += p5.x * v0 + p5.y * v1 + p5.z * v2 + p5.w * v3;
            o[6] += p6.x * v0 + p6.y * v1 + p6.z * v2 + p6.w * v3;
            o[7] += p7.x * v0 + p7.y * v1 + p7.z * v2 + p7.w * v3;
        }
#pragma unroll
        for (int s = 0; s < 8; ++s)
            xout[((size_t)(b * S_ + s0 + s)) * CC + h * HD + d] = f2bf(o[s] * rsum[s]);
    }
}

// ---------------------------------------------------------------- p_t head
__global__ __launch_bounds__(128) void pt_kernel(const float* __restrict__ T,
    const float* __restrict__ vpw, const float* __restrict__ vpb,
    float* __restrict__ out) {
    int row = blockIdx.x;
    int t = threadIdx.x;
    const float* x = T + (size_t)row * C_;
    float s = x[t] * vpw[t] + x[t + 128] * vpw[t + 128] + x[t + 256] * vpw[t + 256];
    __shared__ float red[128];
    red[t] = s; __syncthreads();
    if (t < 64) {
        s = red[t] + red[t + 64];
        for (int o = 32; o; o >>= 1) s += __shfl_down(s, o);
        if (t == 0) {
            float z = s + vpb[0];
            out[row] = 512.0f / (1.0f + expf(-z));
        }
    }
}

// ---------------------------------------------------------------- launch
extern "C" void kernel_launch(void* const* d_in, const int* in_sizes, int n_in,
                              void* d_out, int out_size, void* d_ws, size_t ws_size,
                              hipStream_t stream) {
    const float* q     = (const float*)d_in[0];
    const float* kv    = (const float*)d_in[1];
    const float* Wq    = (const float*)d_in[2];
    const float* Wkv   = (const float*)d_in[3];
    const float* Wproj = (const float*)d_in[4];
    const float* bproj = (const float*)d_in[5];
    const float* Wp_w  = (const float*)d_in[6];
    const float* Wp_b  = (const float*)d_in[7];
    const float* vp_w  = (const float*)d_in[8];
    const float* vp_b  = (const float*)d_in[9];
    const float* Wqpos = (const float*)d_in[10];
    const float* bqpos = (const float*)d_in[11];
    const float* Wrctc = (const float*)d_in[12];
    const float* brctc = (const float*)d_in[13];
    const float* ca1_Wq    = (const float*)d_in[14];
    const float* ca1_Wkv   = (const float*)d_in[15];
    const float* ca1_Wproj = (const float*)d_in[16];
    const float* ca1_bproj = (const float*)d_in[17];
    const float* ca2_Wq    = (const float*)d_in[18];
    const float* ca2_Wkv   = (const float*)d_in[19];
    const float* ca2_Wproj = (const float*)d_in[20];
    const float* ca2_bproj = (const float*)d_in[21];
    const float* g_q1  = (const float*)d_in[22];
    const float* b_q1  = (const float*)d_in[23];
    const float* g_kv1 = (const float*)d_in[24];
    const float* b_kv1 = (const float*)d_in[25];
    const float* g_q2  = (const float*)d_in[26];
    const float* b_q2  = (const float*)d_in[27];
    const float* g_kv2 = (const float*)d_in[28];
    const float* b_kv2 = (const float*)d_in[29];
    float* out = (float*)d_out;
    float* ws  = (float*)d_ws;

    // workspace layout (float offsets), total 38858752 floats ~ 155.4 MB
    float*  dec   = ws;                              // 6291456 fl
    ushort* dec0b = (ushort*)(ws + 6291456);         // 6291456 ush
    ushort* wb    = (ushort*)(ws + 9437184);         // 2211840 ush
    ushort* qb    = (ushort*)(ws + 10543104);        // 1572864 ush
    ushort* decb  = (ushort*)(ws + 11329536);        // 6291456 ush
    float*  qh    = ws + 14475264;                   // 1572864 fl
    float*  p     = ws + 16048128;                   // 1572864 fl
    ushort* pb    = (ushort*)(ws + 17620992);        // 1572864 ush
    float*  t1    = ws + 18407424;                   // 1572864 fl
    ushort* t1b   = (ushort*)(ws + 19980288);        // 1572864 ush
    ushort* t2b   = (ushort*)(ws + 20766720);        // 6291456 ush
    float*  qp    = ws + 23912448;                   // 1572864 fl
    float*  kvp   = ws + 25485312;                   // 12582912 fl
    ushort* xb    = (ushort*)(ws + 38068224);        // 1572864 ush
    float*  ptb   = ws + 38854656;                   // 4096 fl

    // bf16 transposed weight sub-offsets (ushort units)
    ushort* wbWq     = wb;
    ushort* wbWqpos  = wb + 147456;
    ushort* wbWrctc  = wb + 294912;
    ushort* wbC1Wq   = wb + 442368;
    ushort* wbC1Wp   = wb + 589824;
    ushort* wbC2Wq   = wb + 737280;
    ushort* wbC2Wp   = wb + 884736;
    ushort* wbWpw    = wb + 1032192;
    ushort* wbWproj  = wb + 1179648;
    ushort* wbWkv    = wb + 1327104;
    ushort* wbC1Wkv  = wb + 1622016;
    ushort* wbC2Wkv  = wb + 1916928;

    const float rs384 = 0.05103103630798288f;  // 1/sqrt(384)
    const float rs192 = 0.07216878364870323f;  // 1/sqrt(192)

    // 1. mean over H -> bf16
    {
        int total = B_ * W_ * (C_ / 4);
        mean_kernel<<<(total + 255) / 256, 256, 0, stream>>>(kv, dec0b);
    }
    // 2. weight transpose-casts (one launch) + q cast
    {
        WtDesc d;
        const float* s_[12] = {Wq, Wqpos, Wrctc, ca1_Wq, ca1_Wproj, ca2_Wq, ca2_Wproj,
                               Wp_w, Wproj, Wkv, ca1_Wkv, ca2_Wkv};
        ushort* t_[12] = {wbWq, wbWqpos, wbWrctc, wbC1Wq, wbC1Wp, wbC2Wq, wbC2Wp,
                          wbWpw, wbWproj, wbWkv, wbC1Wkv, wbC2Wkv};
        for (int i = 0; i < 12; ++i) {
            d.src[i] = s_[i]; d.dst[i] = t_[i];
            d.Kd[i] = 384; d.Nd[i] = (i >= 9) ? 768 : 384;
        }
        dim3 grid((294912 + 255) / 256, 12);
        wtcast_kernel<<<grid, 256, 0, stream>>>(d);
        cast_kernel<<<(393216 + 255) / 256, 256, 0, stream>>>(q, qb, 393216);
    }
    // 3. dec = dec0 @ Wrctc + brctc  (fp32 + bf16 outputs)
    bgemm(stream, dec0b, wbWrctc, brctc, dec, decb, B_ * W_, 384, 384, 1.f, 0);
    // 4. qh = (q @ Wq) * rs384 ; p = q @ Wqpos + bqpos
    bgemm(stream, qb, wbWq, nullptr, qh, nullptr, B_ * S_, 384, 384, rs384, 0);
    bgemm(stream, qb, wbWqpos, bqpos, p, nullptr, B_ * S_, 384, 384, 1.f, 0);
    // 5. ca1
    ln_kernel<<<B_ * S_, 128, 0, stream>>>(p, g_q1, b_q1, t1b);
    ln_kernel<<<B_ * S_, 128, 0, stream>>>(q, g_kv1, b_kv1, t2b);
    bgemm(stream, t1b, wbC1Wq, nullptr, qp, nullptr, B_ * S_, 384, 384, rs192, 0);
    bgemm(stream, t2b, wbC1Wkv, nullptr, kvp, nullptr, B_ * S_, 768, 384, 1.f, 0);
    attn_kernel<192, 2, 0><<<B_ * 2 * (S_ / 8), 256, 0, stream>>>(qp, kvp, nullptr, xb, S_);
    bgemm(stream, xb, wbC1Wp, ca1_bproj, p, nullptr, B_ * S_, 384, 384, 1.f, 0);
    // 6. ca2
    ln_kernel<<<B_ * S_, 128, 0, stream>>>(p, g_q2, b_q2, t1b);
    ln_kernel<<<B_ * W_, 128, 0, stream>>>(dec, g_kv2, b_kv2, t2b);
    bgemm(stream, t1b, wbC2Wq, nullptr, qp, nullptr, B_ * S_, 384, 384, rs192, 0);
    bgemm(stream, t2b, wbC2Wkv, nullptr, kvp, nullptr, B_ * W_, 768, 384, 1.f, 0);
    attn_kernel<192, 2, 0><<<B_ * 2 * (S_ / 8), 256, 0, stream>>>(qp, kvp, nullptr, xb, W_);
    bgemm(stream, xb, wbC2Wp, ca2_bproj, p, pb, B_ * S_, 384, 384, 1.f, 0);
    // 7. p_t head
    bgemm(stream, pb, wbWpw, Wp_b, t1, nullptr, B_ * S_, 384, 384, 1.f, 1);
    pt_kernel<<<B_ * S_, 128, 0, stream>>>(t1, vp_w, vp_b, ptb);
    // 8. main k/v = dec @ Wkv
    bgemm(stream, decb, wbWkv, nullptr, kvp, nullptr, B_ * W_, 768, 384, 1.f, 0);
    // 9. gauss-windowed attention
    attn_kernel<384, 1, 1><<<B_ * 1 * (S_ / 8), 256, 0, stream>>>(qh, kvp, ptb, xb, W_);
    // 10. out = x @ Wproj + bproj
    bgemm(stream, xb, wbWproj, bproj, out, nullptr, B_ * S_, 384, 384, 1.f, 0);
}

// Round 3
// 613.964 us; speedup vs baseline: 4.5474x; 1.9360x over previous
//
#include <hip/hip_runtime.h>
#include <hip/hip_bf16.h>
#include <math.h>

#define B_ 32
#define S_ 128
#define C_ 384
#define H_ 8
#define W_ 512
#define NKV 4096   // H_*W_

typedef __attribute__((ext_vector_type(8))) short short8;
typedef __attribute__((ext_vector_type(4))) float floatx4;

static __device__ __forceinline__ ushort f2bf(float v) {
    __hip_bfloat16 h = __float2bfloat16(v);
    return *(ushort*)&h;
}
static __device__ __forceinline__ float ldf(const float* p, size_t i) { return p[i]; }
static __device__ __forceinline__ float ldf(const ushort* p, size_t i) {
    union { uint u; float f; } c; c.u = (uint)p[i] << 16; return c.f;
}

// ---------------------------------------------------------------- mean over H -> bf16
__global__ __launch_bounds__(256) void mean_kernel(const float* __restrict__ kv,
                                                   ushort* __restrict__ dec0b) {
    int v = blockIdx.x * blockDim.x + threadIdx.x;  // float4 index over (B,W,C)
    int total = B_ * W_ * (C_ / 4);
    if (v >= total) return;
    int c4  = v % (C_ / 4);
    int row = v / (C_ / 4);      // b*W + w
    int b = row / W_;
    int w = row % W_;
    const float4* src = (const float4*)kv + (size_t)(b * NKV + w) * (C_ / 4) + c4;
    float4 s = {0.f, 0.f, 0.f, 0.f};
#pragma unroll
    for (int h = 0; h < H_; ++h) {
        float4 t = src[(size_t)h * W_ * (C_ / 4)];
        s.x += t.x; s.y += t.y; s.z += t.z; s.w += t.w;
    }
    ushort4 o;
    o.x = f2bf(s.x * 0.125f); o.y = f2bf(s.y * 0.125f);
    o.z = f2bf(s.z * 0.125f); o.w = f2bf(s.w * 0.125f);
    ((ushort4*)dec0b)[v] = o;
}

// ---------------------------------------------------------------- cast fp32 -> bf16
__global__ __launch_bounds__(256) void cast_kernel(const float* __restrict__ in,
                                                   ushort* __restrict__ out, int n4) {
    int v = blockIdx.x * blockDim.x + threadIdx.x;
    if (v >= n4) return;
    float4 f = ((const float4*)in)[v];
    ushort4 o;
    o.x = f2bf(f.x); o.y = f2bf(f.y); o.z = f2bf(f.z); o.w = f2bf(f.w);
    ((ushort4*)out)[v] = o;
}

// ------------------------------------------------- weight transpose+cast (K,N)->(N,K)
struct WtDesc { const float* src[12]; ushort* dst[12]; int Kd[12]; int Nd[12]; };
__global__ __launch_bounds__(256) void wtcast_kernel(WtDesc d) {
    int wi = blockIdx.y;
    int idx = blockIdx.x * 256 + threadIdx.x;
    int K = d.Kd[wi], N = d.Nd[wi];
    if (idx >= K * N) return;
    int n = idx / K, k = idx % K;
    d.dst[wi][idx] = f2bf(d.src[wi][(size_t)k * N + n]);
}

// ---------------------------------------------------------------- bf16 MFMA GEMM 128x128
__global__ __launch_bounds__(256) void bgemm_kernel(
    const ushort* __restrict__ A, const ushort* __restrict__ Bt,
    const float* __restrict__ bias, float* __restrict__ Cout,
    ushort* __restrict__ Cbf, int M, int N, int K, float alpha, int act)
{
    __shared__ ushort As[128 * 40];
    __shared__ ushort Bs[128 * 40];
    const int tid = threadIdx.x;
    const int bm = blockIdx.y * 128, bn = blockIdx.x * 128;
    const int wav = tid >> 6, lane = tid & 63;
    const int wm = (wav >> 1) * 64, wn = (wav & 1) * 64;
    const int lrow = lane & 15, lq = lane >> 4;

    floatx4 acc[4][4] = {};

    const int sr = tid >> 1, sc0 = (tid & 1) * 16;
    const ushort* Ag = A + (size_t)(bm + sr) * K + sc0;
    const ushort* Bg = Bt + (size_t)(bn + sr) * K + sc0;
    ushort* Asw = &As[sr * 40 + sc0];
    ushort* Bsw = &Bs[sr * 40 + sc0];

    for (int k0 = 0; k0 < K; k0 += 32) {
        uint4 a0 = *(const uint4*)(Ag + k0);
        uint4 a1 = *(const uint4*)(Ag + k0 + 8);
        uint4 b0 = *(const uint4*)(Bg + k0);
        uint4 b1 = *(const uint4*)(Bg + k0 + 8);
        __syncthreads();
        *(uint4*)Asw = a0; *(uint4*)(Asw + 8) = a1;
        *(uint4*)Bsw = b0; *(uint4*)(Bsw + 8) = b1;
        __syncthreads();
        short8 af[4], bfr[4];
#pragma unroll
        for (int i = 0; i < 4; ++i)
            af[i] = *(const short8*)&As[(wm + 16 * i + lrow) * 40 + lq * 8];
#pragma unroll
        for (int j = 0; j < 4; ++j)
            bfr[j] = *(const short8*)&Bs[(wn + 16 * j + lrow) * 40 + lq * 8];
#pragma unroll
        for (int i = 0; i < 4; ++i)
#pragma unroll
            for (int j = 0; j < 4; ++j)
                acc[i][j] = __builtin_amdgcn_mfma_f32_16x16x32_bf16(af[i], bfr[j], acc[i][j], 0, 0, 0);
    }

#pragma unroll
    for (int i = 0; i < 4; ++i)
#pragma unroll
        for (int j = 0; j < 4; ++j) {
            int row = bm + wm + 16 * i + lq * 4;
            int col = bn + wn + 16 * j + lrow;
            float bv = bias ? bias[col] : 0.f;
#pragma unroll
            for (int r = 0; r < 4; ++r) {
                float v = acc[i][j][r] * alpha + bv;
                if (act == 1) v = tanhf(v);
                size_t off = (size_t)(row + r) * N + col;
                if (Cout) Cout[off] = v;
                if (Cbf) Cbf[off] = f2bf(v);
            }
        }
}

static inline void bgemm(hipStream_t st, const ushort* A, const ushort* Bt,
                         const float* bias, float* Cout, ushort* Cbf,
                         int M, int N, int K, float alpha, int act) {
    dim3 grid(N / 128, M / 128), block(256);
    bgemm_kernel<<<grid, block, 0, st>>>(A, Bt, bias, Cout, Cbf, M, N, K, alpha, act);
}

// ------------------------------------------- generic batched 64x64 MFMA GEMM
// batch = bb*NH + hh; operand offset = base + bb*sB + hh*sH; rows stride ld.
struct BGArgs {
    const ushort* A; const ushort* Bt;
    const float* bias; float* outF; ushort* outB;
    int lda, ldb, ldo;
    long AsB, BsB, OsB;
    int AsH, BsH, OsH;
    int K, NH;
    float alpha; int act;
};
__global__ __launch_bounds__(256) void battn_kernel(BGArgs g) {
    __shared__ ushort As[64 * 40];
    __shared__ ushort Bs[64 * 40];
    const int bn = blockIdx.x * 64, bm = blockIdx.y * 64;
    const int bat = blockIdx.z, bb = bat / g.NH, hh = bat % g.NH;
    const ushort* A  = g.A  + (size_t)bb * g.AsB + (size_t)hh * g.AsH;
    const ushort* Bt = g.Bt + (size_t)bb * g.BsB + (size_t)hh * g.BsH;
    const int tid = threadIdx.x;
    const int wav = tid >> 6, lane = tid & 63;
    const int lrow = lane & 15, lq = lane >> 4;
    const int sr = tid >> 2, sc0 = (tid & 3) * 8;
    const ushort* Ag = A  + (size_t)(bm + sr) * g.lda + sc0;
    const ushort* Bg = Bt + (size_t)(bn + sr) * g.ldb + sc0;
    ushort* Asw = &As[sr * 40 + sc0];
    ushort* Bsw = &Bs[sr * 40 + sc0];

    floatx4 acc[4] = {};

    for (int k0 = 0; k0 < g.K; k0 += 32) {
        uint4 a = *(const uint4*)(Ag + k0);
        uint4 b = *(const uint4*)(Bg + k0);
        __syncthreads();
        *(uint4*)Asw = a; *(uint4*)Bsw = b;
        __syncthreads();
        short8 af = *(const short8*)&As[(wav * 16 + lrow) * 40 + lq * 8];
#pragma unroll
        for (int j = 0; j < 4; ++j) {
            short8 bf = *(const short8*)&Bs[(16 * j + lrow) * 40 + lq * 8];
            acc[j] = __builtin_amdgcn_mfma_f32_16x16x32_bf16(af, bf, acc[j], 0, 0, 0);
        }
    }

#pragma unroll
    for (int j = 0; j < 4; ++j) {
        int col = bn + 16 * j + lrow;
        float bv = g.bias ? g.bias[col] : 0.f;
        int row0 = bm + wav * 16 + lq * 4;
#pragma unroll
        for (int r = 0; r < 4; ++r) {
            float v = acc[j][r] * g.alpha + bv;
            if (g.act == 1) v = tanhf(v);
            size_t off = (size_t)bb * g.OsB + (size_t)hh * g.OsH
                       + (size_t)(row0 + r) * g.ldo + col;
            if (g.outF) g.outF[off] = v;
            if (g.outB) g.outB[off] = f2bf(v);
        }
    }
}

static inline void battn(hipStream_t st, const ushort* A, const ushort* Bt,
                         const float* bias, float* outF, ushort* outB,
                         int M, int N, int K, float alpha, int act,
                         int lda, long AsB, int AsH,
                         int ldb, long BsB, int BsH,
                         int ldo, long OsB, int OsH,
                         int NH, int nbat) {
    BGArgs g;
    g.A = A; g.Bt = Bt; g.bias = bias; g.outF = outF; g.outB = outB;
    g.lda = lda; g.ldb = ldb; g.ldo = ldo;
    g.AsB = AsB; g.BsB = BsB; g.OsB = OsB;
    g.AsH = AsH; g.BsH = BsH; g.OsH = OsH;
    g.K = K; g.NH = NH; g.alpha = alpha; g.act = act;
    dim3 grid(N / 64, M / 64, nbat);
    battn_kernel<<<grid, 256, 0, st>>>(g);
}

static inline void bgemm64(hipStream_t st, const ushort* A, const ushort* Bt,
                           const float* bias, float* outF, ushort* outB,
                           int M, int N, int K, float alpha, int act) {
    battn(st, A, Bt, bias, outF, outB, M, N, K, alpha, act,
          K, 0, 0, K, 0, 0, N, 0, 0, 1, 1);
}

// ---------------------------------------------------------------- LayerNorm -> bf16
template <typename T>
__global__ __launch_bounds__(128) void ln_kernel(const T* __restrict__ X,
    const float* __restrict__ g, const float* __restrict__ bb,
    ushort* __restrict__ Y) {
    int row = blockIdx.x;
    const T* x = X + (size_t)row * C_;
    ushort* y = Y + (size_t)row * C_;
    int t = threadIdx.x;
    float v0 = ldf(x, t), v1 = ldf(x, t + 128), v2 = ldf(x, t + 256);
    float s = v0 + v1 + v2, sq = v0 * v0 + v1 * v1 + v2 * v2;
    __shared__ float rs[128], rq[128];
    rs[t] = s; rq[t] = sq; __syncthreads();
    if (t < 64) {
        s = rs[t] + rs[t + 64]; sq = rq[t] + rq[t + 64];
        for (int o = 32; o; o >>= 1) { s += __shfl_down(s, o); sq += __shfl_down(sq, o); }
        if (t == 0) { rs[0] = s; rq[0] = sq; }
    }
    __syncthreads();
    float mean = rs[0] * (1.0f / C_);
    float var  = rq[0] * (1.0f / C_) - mean * mean;
    float inv  = rsqrtf(var + 1e-6f);
    y[t]       = f2bf((v0 - mean) * inv * g[t]       + bb[t]);
    y[t + 128] = f2bf((v1 - mean) * inv * g[t + 128] + bb[t + 128]);
    y[t + 256] = f2bf((v2 - mean) * inv * g[t + 256] + bb[t + 256]);
}

// ------------------------------------------- softmax (+ optional gauss) rows
// sc: (R, NW) fp32; P: (R, NW) bf16 normalized. GAUSS => NH==1, ptv[row].
template <int NW, int GAUSS>
__global__ __launch_bounds__(256) void softmax_kernel(
    const float* __restrict__ sc, const float* __restrict__ ptv,
    ushort* __restrict__ P)
{
    int row = blockIdx.x * 4 + (threadIdx.x >> 6);
    int lane = threadIdx.x & 63;
    const float* s = sc + (size_t)row * NW;
    float pcen = GAUSS ? ptv[row] : 0.f;
    float vals[NW / 64];
    float m = -1e30f;
#pragma unroll
    for (int i = 0; i < NW / 64; ++i) {
        int w = lane + 64 * i;
        float v = s[w];
        if (GAUSS) { float dw = (float)w - pcen; v *= expf(dw * dw * (-1.0f / 18.0f)); }
        vals[i] = v; m = fmaxf(m, v);
    }
#pragma unroll
    for (int o = 32; o; o >>= 1) m = fmaxf(m, __shfl_xor(m, o));
    float sum = 0.f;
#pragma unroll
    for (int i = 0; i < NW / 64; ++i) { vals[i] = expf(vals[i] - m); sum += vals[i]; }
#pragma unroll
    for (int o = 32; o; o >>= 1) sum += __shfl_xor(sum, o);
    float rinv = 1.0f / sum;
    ushort* op = P + (size_t)row * NW;
#pragma unroll
    for (int i = 0; i < NW / 64; ++i) op[lane + 64 * i] = f2bf(vals[i] * rinv);
}

// ------------------------------------------- v transpose: kvb (B*Nw, C2) bf16
// v-part (cols CC..2CC) -> vt (B, CC, Nw) bf16. 32x32 LDS tiles.
__global__ __launch_bounds__(256) void vtrans_kernel(
    const ushort* __restrict__ kvb, ushort* __restrict__ vt,
    int Nw, int C2, int CC)
{
    int b = blockIdx.z;
    int w0 = blockIdx.x * 32, c0 = blockIdx.y * 32;
    __shared__ ushort t[32][33];
    int tid = threadIdx.x;
    int wl = tid >> 3, c4 = (tid & 7) * 4;
    ushort4 v = *(const ushort4*)&kvb[((size_t)b * Nw + w0 + wl) * C2 + CC + c0 + c4];
    t[wl][c4] = v.x; t[wl][c4 + 1] = v.y; t[wl][c4 + 2] = v.z; t[wl][c4 + 3] = v.w;
    __syncthreads();
    int dl = tid >> 3, w4 = (tid & 7) * 4;
    ushort4 o;
    o.x = t[w4][dl]; o.y = t[w4 + 1][dl]; o.z = t[w4 + 2][dl]; o.w = t[w4 + 3][dl];
    *(ushort4*)&vt[((size_t)b * CC + c0 + dl) * Nw + w0 + w4] = o;
}

// ---------------------------------------------------------------- p_t head
__global__ __launch_bounds__(128) void pt_kernel(const float* __restrict__ T,
    const float* __restrict__ vpw, const float* __restrict__ vpb,
    float* __restrict__ out) {
    int row = blockIdx.x;
    int t = threadIdx.x;
    const float* x = T + (size_t)row * C_;
    float s = x[t] * vpw[t] + x[t + 128] * vpw[t + 128] + x[t + 256] * vpw[t + 256];
    __shared__ float red[128];
    red[t] = s; __syncthreads();
    if (t < 64) {
        s = red[t] + red[t + 64];
        for (int o = 32; o; o >>= 1) s += __shfl_down(s, o);
        if (t == 0) {
            float z = s + vpb[0];
            out[row] = 512.0f / (1.0f + expf(-z));
        }
    }
}

// ---------------------------------------------------------------- launch
extern "C" void kernel_launch(void* const* d_in, const int* in_sizes, int n_in,
                              void* d_out, int out_size, void* d_ws, size_t ws_size,
                              hipStream_t stream) {
    const float* q     = (const float*)d_in[0];
    const float* kv    = (const float*)d_in[1];
    const float* Wq    = (const float*)d_in[2];
    const float* Wkv   = (const float*)d_in[3];
    const float* Wproj = (const float*)d_in[4];
    const float* bproj = (const float*)d_in[5];
    const float* Wp_w  = (const float*)d_in[6];
    const float* Wp_b  = (const float*)d_in[7];
    const float* vp_w  = (const float*)d_in[8];
    const float* vp_b  = (const float*)d_in[9];
    const float* Wqpos = (const float*)d_in[10];
    const float* bqpos = (const float*)d_in[11];
    const float* Wrctc = (const float*)d_in[12];
    const float* brctc = (const float*)d_in[13];
    const float* ca1_Wq    = (const float*)d_in[14];
    const float* ca1_Wkv   = (const float*)d_in[15];
    const float* ca1_Wproj = (const float*)d_in[16];
    const float* ca1_bproj = (const float*)d_in[17];
    const float* ca2_Wq    = (const float*)d_in[18];
    const float* ca2_Wkv   = (const float*)d_in[19];
    const float* ca2_Wproj = (const float*)d_in[20];
    const float* ca2_bproj = (const float*)d_in[21];
    const float* g_q1  = (const float*)d_in[22];
    const float* b_q1  = (const float*)d_in[23];
    const float* g_kv1 = (const float*)d_in[24];
    const float* b_kv1 = (const float*)d_in[25];
    const float* g_q2  = (const float*)d_in[26];
    const float* b_q2  = (const float*)d_in[27];
    const float* g_kv2 = (const float*)d_in[28];
    const float* b_kv2 = (const float*)d_in[29];
    float* out = (float*)d_out;
    float* ws  = (float*)d_ws;

    // workspace layout (float offsets), total 34140160 fl ~ 136.6 MB
    ushort* dec0b = (ushort*)(ws);                   // 6291456 ush
    ushort* wb    = (ushort*)(ws + 3145728);         // 2211840 ush
    ushort* qb    = (ushort*)(ws + 4251648);         // 1572864 ush
    ushort* decb  = (ushort*)(ws + 5038080);         // 6291456 ush
    ushort* qhb   = (ushort*)(ws + 8183808);         // 1572864 ush
    float*  p     = ws + 8970240;                    // 1572864 fl
    ushort* pb    = (ushort*)(ws + 10543104);        // 1572864 ush
    float*  t1    = ws + 11329536;                   // 1572864 fl
    ushort* t1b   = (ushort*)(ws + 12902400);        // 1572864 ush
    ushort* t2b   = (ushort*)(ws + 13688832);        // 6291456 ush
    ushort* qpb   = (ushort*)(ws + 16834560);        // 1572864 ush
    ushort* kvb   = (ushort*)(ws + 17620992);        // 12582912 ush
    ushort* vt    = (ushort*)(ws + 23912448);        // 6291456 ush
    float*  sc    = ws + 27058176;                   // 4194304 fl
    ushort* Pb    = (ushort*)(ws + 31252480);        // 4194304 ush
    ushort* xb    = (ushort*)(ws + 33349632);        // 1572864 ush
    float*  ptb   = ws + 34136064;                   // 4096 fl

    // bf16 transposed weight sub-offsets (ushort units)
    ushort* wbWq     = wb;
    ushort* wbWqpos  = wb + 147456;
    ushort* wbWrctc  = wb + 294912;
    ushort* wbC1Wq   = wb + 442368;
    ushort* wbC1Wp   = wb + 589824;
    ushort* wbC2Wq   = wb + 737280;
    ushort* wbC2Wp   = wb + 884736;
    ushort* wbWpw    = wb + 1032192;
    ushort* wbWproj  = wb + 1179648;
    ushort* wbWkv    = wb + 1327104;
    ushort* wbC1Wkv  = wb + 1622016;
    ushort* wbC2Wkv  = wb + 1916928;

    const float rs384 = 0.05103103630798288f;  // 1/sqrt(384)
    const float rs192 = 0.07216878364870323f;  // 1/sqrt(192)

    // 1. mean over H -> bf16
    mean_kernel<<<(B_ * W_ * (C_ / 4) + 255) / 256, 256, 0, stream>>>(kv, dec0b);
    // 2. weight transpose-casts + q cast
    {
        WtDesc d;
        const float* s_[12] = {Wq, Wqpos, Wrctc, ca1_Wq, ca1_Wproj, ca2_Wq, ca2_Wproj,
                               Wp_w, Wproj, Wkv, ca1_Wkv, ca2_Wkv};
        ushort* t_[12] = {wbWq, wbWqpos, wbWrctc, wbC1Wq, wbC1Wp, wbC2Wq, wbC2Wp,
                          wbWpw, wbWproj, wbWkv, wbC1Wkv, wbC2Wkv};
        for (int i = 0; i < 12; ++i) {
            d.src[i] = s_[i]; d.dst[i] = t_[i];
            d.Kd[i] = 384; d.Nd[i] = (i >= 9) ? 768 : 384;
        }
        dim3 grid((294912 + 255) / 256, 12);
        wtcast_kernel<<<grid, 256, 0, stream>>>(d);
        cast_kernel<<<(393216 + 255) / 256, 256, 0, stream>>>(q, qb, 393216);
    }
    // 3. dec = dec0 @ Wrctc + brctc -> bf16 only
    bgemm(stream, dec0b, wbWrctc, brctc, nullptr, decb, B_ * W_, 384, 384, 1.f, 0);
    // 4. qh bf16 = (q @ Wq)*rs384 ; p fp32 = q @ Wqpos + bqpos
    bgemm64(stream, qb, wbWq, nullptr, nullptr, qhb, B_ * S_, 384, 384, rs384, 0);
    bgemm64(stream, qb, wbWqpos, bqpos, p, nullptr, B_ * S_, 384, 384, 1.f, 0);
    // 5. ca1
    ln_kernel<float><<<B_ * S_, 128, 0, stream>>>(p, g_q1, b_q1, t1b);
    ln_kernel<float><<<B_ * S_, 128, 0, stream>>>(q, g_kv1, b_kv1, t2b);
    bgemm64(stream, t1b, wbC1Wq, nullptr, nullptr, qpb, B_ * S_, 384, 384, rs192, 0);
    bgemm64(stream, t2b, wbC1Wkv, nullptr, nullptr, kvb, B_ * S_, 768, 384, 1.f, 0);
    {
        dim3 gt(S_ / 32, C_ / 32, B_);
        vtrans_kernel<<<gt, 256, 0, stream>>>(kvb, vt, S_, 768, 384);
    }
    battn(stream, qpb, kvb, nullptr, sc, nullptr, 128, 128, 192, 1.f, 0,
          384, (long)S_ * 384, 192,
          768, (long)S_ * 768, 192,
          128, (long)2 * S_ * 128, S_ * 128, 2, 64);
    softmax_kernel<128, 0><<<(B_ * 2 * S_) / 4, 256, 0, stream>>>(sc, nullptr, Pb);
    battn(stream, Pb, vt, nullptr, nullptr, xb, 128, 192, 128, 1.f, 0,
          128, (long)2 * S_ * 128, S_ * 128,
          128, (long)C_ * S_, 192 * S_,
          384, (long)S_ * 384, 192, 2, 64);
    bgemm64(stream, xb, wbC1Wp, ca1_bproj, p, nullptr, B_ * S_, 384, 384, 1.f, 0);
    // 6. ca2
    ln_kernel<float><<<B_ * S_, 128, 0, stream>>>(p, g_q2, b_q2, t1b);
    ln_kernel<ushort><<<B_ * W_, 128, 0, stream>>>(decb, g_kv2, b_kv2, t2b);
    bgemm64(stream, t1b, wbC2Wq, nullptr, nullptr, qpb, B_ * S_, 384, 384, rs192, 0);
    bgemm(stream, t2b, wbC2Wkv, nullptr, nullptr, kvb, B_ * W_, 768, 384, 1.f, 0);
    {
        dim3 gt(W_ / 32, C_ / 32, B_);
        vtrans_kernel<<<gt, 256, 0, stream>>>(kvb, vt, W_, 768, 384);
    }
    battn(stream, qpb, kvb, nullptr, sc, nullptr, 128, 512, 192, 1.f, 0,
          384, (long)S_ * 384, 192,
          768, (long)W_ * 768, 192,
          512, (long)2 * S_ * 512, S_ * 512, 2, 64);
    softmax_kernel<512, 0><<<(B_ * 2 * S_) / 4, 256, 0, stream>>>(sc, nullptr, Pb);
    battn(stream, Pb, vt, nullptr, nullptr, xb, 128, 192, 512, 1.f, 0,
          512, (long)2 * S_ * 512, S_ * 512,
          512, (long)C_ * W_, 192 * W_,
          384, (long)S_ * 384, 192, 2, 64);
    bgemm64(stream, xb, wbC2Wp, ca2_bproj, p, pb, B_ * S_, 384, 384, 1.f, 0);
    // 7. p_t head
    bgemm64(stream, pb, wbWpw, Wp_b, t1, nullptr, B_ * S_, 384, 384, 1.f, 1);
    pt_kernel<<<B_ * S_, 128, 0, stream>>>(t1, vp_w, vp_b, ptb);
    // 8. main k/v = dec @ Wkv -> bf16
    bgemm(stream, decb, wbWkv, nullptr, nullptr, kvb, B_ * W_, 768, 384, 1.f, 0);
    {
        dim3 gt(W_ / 32, C_ / 32, B_);
        vtrans_kernel<<<gt, 256, 0, stream>>>(kvb, vt, W_, 768, 384);
    }
    // 9. main attention: scores, gauss-softmax, PV
    battn(stream, qhb, kvb, nullptr, sc, nullptr, 128, 512, 384, 1.f, 0,
          384, (long)S_ * 384, 0,
          768, (long)W_ * 768, 0,
          512, (long)S_ * 512, 0, 1, 32);
    softmax_kernel<512, 1><<<(B_ * S_) / 4, 256, 0, stream>>>(sc, ptb, Pb);
    battn(stream, Pb, vt, nullptr, nullptr, xb, 128, 384, 512, 1.f, 0,
          512, (long)S_ * 512, 0,
          512, (long)C_ * W_, 0,
          384, (long)S_ * 384, 0, 1, 32);
    // 10. out = x @ Wproj + bproj (fp32)
    bgemm64(stream, xb, wbWproj, bproj, out, nullptr, B_ * S_, 384, 384, 1.f, 0);
}